// Round 8
// baseline (217.771 us; speedup 1.0000x reference)
//
#include <hip/hip_runtime.h>
#include <math.h>

#define NSAMPLE 32
constexpr int B_ = 2, N_ = 8192, C_ = 64, C1_ = 128, C2_ = 128, CIN_ = 67;
constexpr int KP = 96;            // padded Cin for GEMM1 (3 k-steps of 32)
constexpr int XPAD = 104;         // XT row stride
constexpr int HPAD = 136;         // HT row stride
constexpr float BQ_R2 = 0.15f * 0.15f;
constexpr float EPS_ = 1e-5f;
constexpr int NCELL = 216;        // 6x6x6 grid, cell 1/6 > r

typedef __attribute__((ext_vector_type(8))) short bf16x8;
typedef __attribute__((ext_vector_type(4))) short short4v;
typedef __attribute__((ext_vector_type(4))) float f32x4;
typedef unsigned long long ull;

__device__ __forceinline__ short f2bf(float x) {            // RNE
    union { float f; unsigned u; } v; v.f = x;
    return (short)((v.u + 0x7FFFu + ((v.u >> 16) & 1u)) >> 16);
}
__device__ __forceinline__ int cell_id(float x, float y, float z) {
    int cx = min((int)(x * 6.0f), 5);
    int cy = min((int)(y * 6.0f), 5);
    int cz = min((int)(z * 6.0f), 5);
    return (cz * 6 + cy) * 6 + cx;
}

// ---- prep: blocks [0,64) transpose f; block 64 weights/BN; [65,129) cell-count
constexpr int TBLK = (B_ * N_) / 256;        // 64
constexpr int CBLK0 = TBLK + 1;              // 65

__global__ __launch_bounds__(256) void prep_kernel(
    const float* __restrict__ p, const float* __restrict__ f,
    short* __restrict__ fT, int* __restrict__ counts,
    const float* __restrict__ W1,
    const float* __restrict__ g1, const float* __restrict__ b1,
    const float* __restrict__ m1, const float* __restrict__ v1,
    const float* __restrict__ W2,
    const float* __restrict__ g2, const float* __restrict__ b2,
    const float* __restrict__ m2, const float* __restrict__ v2,
    short* __restrict__ W1p, short* __restrict__ W2p, float* __restrict__ bn)
{
    int blk = blockIdx.x;
    if (blk < TBLK) {
        // transpose f [B,C,N] fp32 -> fT [B*N][64] bf16
        int g = blk * 256 + threadIdx.x;
        int b = g >> 13, n = g & (N_ - 1);
        const float* fb = f + (size_t)b * C_ * N_ + n;     // coalesced over n
        short* row = fT + (size_t)g * C_;
        #pragma unroll
        for (int c0 = 0; c0 < C_; c0 += 8) {
            bf16x8 v;
            #pragma unroll
            for (int c = 0; c < 8; ++c) v[c] = f2bf(fb[(size_t)(c0 + c) * N_]);
            *(bf16x8*)&row[c0] = v;
        }
    } else if (blk == TBLK) {
        if (threadIdx.x >= 128) return;
        int t = threadIdx.x;
        short* r1 = W1p + t * KP;     // k 0..2 dp, 3..7 zero, 8..71 f, 72..95 zero
        #pragma unroll
        for (int k = 0; k < 3; ++k) r1[k] = f2bf(W1[t * CIN_ + k]);
        #pragma unroll
        for (int k = 3; k < 8; ++k) r1[k] = 0;
        for (int c = 0; c < 64; ++c) r1[8 + c] = f2bf(W1[t * CIN_ + 3 + c]);
        #pragma unroll
        for (int k = 72; k < KP; ++k) r1[k] = 0;
        short* r2 = W2p + t * C1_;
        for (int c = 0; c < C1_; ++c) r2[c] = f2bf(W2[t * C1_ + c]);
        float s1 = g1[t] * rsqrtf(v1[t] + EPS_);
        bn[t] = s1;            bn[128 + t] = b1[t] - m1[t] * s1;
        float s2 = g2[t] * rsqrtf(v2[t] + EPS_);
        bn[256 + t] = s2;      bn[384 + t] = b2[t] - m2[t] * s2;
    } else {
        // cell counting
        int g = (blk - CBLK0) * 256 + threadIdx.x;         // 0..B*N-1
        int b = g >> 13, n = g & (N_ - 1);
        const float* q = p + (size_t)b * N_ * 3 + 3 * n;
        int c = cell_id(q[0], q[1], q[2]);
        atomicAdd(&counts[b * 256 + c], 1);
    }
}

// ---- prefix: wave b scans counts[b][0..215] -> starts[b][0..216] ----------
__global__ __launch_bounds__(128) void prefix_kernel(
    const int* __restrict__ counts, int* __restrict__ starts)
{
    int w = threadIdx.x >> 6, lane = threadIdx.x & 63;
    const int* cnt = counts + w * 256;
    int* st = starts + w * 256;
    int off = 0;
    #pragma unroll
    for (int ch = 0; ch < 4; ++ch) {
        int i = ch * 64 + lane;
        int v = (i < NCELL) ? cnt[i] : 0;
        int incl = v;
        #pragma unroll
        for (int d = 1; d < 64; d <<= 1) {
            int t = __shfl_up(incl, d, 64);
            if (lane >= d) incl += t;
        }
        if (i <= NCELL) st[i] = off + incl - v;
        off += __shfl(incl, 63, 64);
    }
}

// ---- scatter: point -> its cell's list slot (order within cell arbitrary) -
__global__ __launch_bounds__(256) void scatter_kernel(
    const float* __restrict__ p, const int* __restrict__ starts,
    int* __restrict__ cursors, int* __restrict__ lists)
{
    int g = blockIdx.x * 256 + threadIdx.x;
    int b = g >> 13, n = g & (N_ - 1);
    const float* q = p + (size_t)b * N_ * 3 + 3 * n;
    int c = cell_id(q[0], q[1], q[2]);
    int slot = starts[b * 256 + c] + atomicAdd(&cursors[b * 256 + c], 1);
    lists[(b << 13) + slot] = n;
}

// ---- grid query: wave per point; 27-cell candidates -> LDS bitmap ->
//      extract 32 lowest set bits (= first 32 hits by index) ---------------
__global__ __launch_bounds__(256) void grid_query_kernel(
    const float* __restrict__ p, const int* __restrict__ starts,
    const int* __restrict__ lists, int* __restrict__ idx)
{
    __shared__ ull bitmap[4][128];
    int tid = threadIdx.x, lane = tid & 63, w = tid >> 6;
    int wid = blockIdx.x * 4 + w;             // 0..B*N-1
    int b = wid >> 13, n = wid & (N_ - 1);
    const float* pb = p + (size_t)b * N_ * 3;
    const int* st = starts + b * 256;
    const int* ls = lists + (b << 13);
    float qx = pb[3 * n], qy = pb[3 * n + 1], qz = pb[3 * n + 2];

    #pragma unroll
    for (int i = lane; i < 128; i += 64) bitmap[w][i] = 0;

    int cx = min((int)(qx * 6.0f), 5);
    int cy = min((int)(qy * 6.0f), 5);
    int cz = min((int)(qz * 6.0f), 5);
    int x0 = max(cx - 1, 0), x1 = min(cx + 1, 5);

    // 9 (z,y) rows; x-range is contiguous in the list -> 9 segments
    int segBase[9], segLen[9], total = 0;
    #pragma unroll
    for (int s = 0; s < 9; ++s) {
        int zz = cz - 1 + s / 3, yy = cy - 1 + s % 3;
        bool ok = (zz >= 0 && zz < 6 && yy >= 0 && yy < 6);
        int zc = min(max(zz, 0), 5), yc = min(max(yy, 0), 5);
        int row = (zc * 6 + yc) * 6;
        int s0 = st[row + x0], s1 = st[row + x1 + 1];
        segBase[s] = s0;
        segLen[s] = ok ? (s1 - s0) : 0;
        total += segLen[s];
    }

    for (int o0 = 0; o0 < total; o0 += 64) {
        int o = o0 + lane;
        if (o < total) {
            // map flat ordinal -> (segment, offset); fully unrolled, no dyn index
            int rem = o, addr = -1;
            #pragma unroll
            for (int s = 0; s < 9; ++s) {
                if (rem >= 0 && rem < segLen[s] && addr < 0) addr = segBase[s] + rem;
                rem -= segLen[s];
            }
            int j = ls[addr];
            float dx = __fadd_rn(pb[3 * j],     -qx);
            float dy = __fadd_rn(pb[3 * j + 1], -qy);
            float dz = __fadd_rn(pb[3 * j + 2], -qz);
            float d2 = __fadd_rn(__fadd_rn(__fmul_rn(dx, dx), __fmul_rn(dy, dy)),
                                 __fmul_rn(dz, dz));
            if (d2 < BQ_R2)
                atomicOr(&bitmap[w][j >> 6], 1ull << (j & 63));
        }
    }
    __threadfence_block();   // order ds_or before ds_read (wave-private buffer)

    // extraction: lane owns words 2*lane, 2*lane+1
    ull w0 = bitmap[w][2 * lane], w1 = bitmap[w][2 * lane + 1];
    int c = __popcll(w0) + __popcll(w1);
    int incl = c;
    #pragma unroll
    for (int d = 1; d < 64; d <<= 1) {
        int t = __shfl_up(incl, d, 64);
        if (lane >= d) incl += t;
    }
    int pref = incl - c;
    int total_hits = __shfl(incl, 63, 64);
    int* out = idx + (size_t)wid * NSAMPLE;

    int rank = pref;
    ull ww = w0;
    int basebit = lane * 128;
    while (ww && rank < NSAMPLE) {
        int bpos = __builtin_ctzll(ww);
        out[rank] = basebit + bpos;
        ++rank; ww &= ww - 1;
    }
    ww = w1; basebit += 64;
    while (ww && rank < NSAMPLE) {
        int bpos = __builtin_ctzll(ww);
        out[rank] = basebit + bpos;
        ++rank; ww &= ww - 1;
    }

    if (total_hits < NSAMPLE) {         // pad with first hit (always >=1: self)
        ull m = __ballot(c > 0);
        int l0 = __ffsll((long long)m) - 1;
        int fb_local = w0 ? __builtin_ctzll(w0) : 64 + __builtin_ctzll(w1);
        int first = __shfl(fb_local, l0, 64) + l0 * 128;
        for (int k2 = total_hits + lane; k2 < NSAMPLE; k2 += 64) out[k2] = first;
    }
}

// ---- fused: gather + GEMM1+BN/ReLU + GEMM2+BN + max (round-4 version) -----
__global__ __launch_bounds__(256) void fused_mfma_kernel(
    const float* __restrict__ p, const int* __restrict__ idx,
    const short* __restrict__ fT, const short* __restrict__ W1p,
    const short* __restrict__ W2p, const float* __restrict__ bn,
    float* __restrict__ out)
{
    __shared__ short smem[128 * HPAD];   // 34816 B, XT/HT union
    __shared__ float sBN[4][128];
    __shared__ int sidx[128];

    int tid = threadIdx.x;
    int bk = blockIdx.x;
    bk = (bk & 7) * 512 + (bk >> 3);     // XCD-contiguous swizzle (4096 = 8*512)
    int b = bk >> 11;
    int n0 = (bk & 2047) * 4;
    int lane = tid & 63, w = tid >> 6;
    int lr = lane & 15, lq = lane >> 4;

    if (tid < 128) {
        sBN[0][tid] = bn[tid];       sBN[1][tid] = bn[128 + tid];
        sBN[2][tid] = bn[256 + tid]; sBN[3][tid] = bn[384 + tid];
        sidx[tid] = idx[((size_t)((b << 13) + n0)) * NSAMPLE + tid];
    }
    __syncthreads();

    const float* pb = p + (size_t)b * N_ * 3;
    #pragma unroll
    for (int pass = 0; pass < 4; ++pass) {
        int col = pass * 32 + (tid >> 3);
        int part = tid & 7;
        int j = sidx[col];
        *(bf16x8*)&smem[col * XPAD + 8 + part * 8] =
            *(const bf16x8*)&fT[((size_t)(b << 13) + j) * C_ + part * 8];
        if (part == 0) {
            int n = n0 + (col >> 5);
            bf16x8 v = {0, 0, 0, 0, 0, 0, 0, 0};
            v[0] = f2bf(__fadd_rn(pb[3 * j],     -pb[3 * n]));
            v[1] = f2bf(__fadd_rn(pb[3 * j + 1], -pb[3 * n + 1]));
            v[2] = f2bf(__fadd_rn(pb[3 * j + 2], -pb[3 * n + 2]));
            *(bf16x8*)&smem[col * XPAD] = v;
        } else if (part <= 3) {
            bf16x8 z = {0, 0, 0, 0, 0, 0, 0, 0};
            *(bf16x8*)&smem[col * XPAD + 72 + (part - 1) * 8] = z;
        }
    }
    __syncthreads();

    int wr = (w & 1) * 64;
    int wc = (w >> 1) * 64;

    f32x4 acc[4][4];
    #pragma unroll
    for (int m = 0; m < 4; ++m)
        #pragma unroll
        for (int nt = 0; nt < 4; ++nt) acc[m][nt] = (f32x4){0.f, 0.f, 0.f, 0.f};
    #pragma unroll
    for (int ks = 0; ks < 3; ++ks) {
        bf16x8 a[4];
        #pragma unroll
        for (int m = 0; m < 4; ++m)
            a[m] = *(const bf16x8*)&W1p[(wr + m * 16 + lr) * KP + ks * 32 + lq * 8];
        #pragma unroll
        for (int nt = 0; nt < 4; ++nt) {
            bf16x8 bf = *(const bf16x8*)&smem[(wc + nt * 16 + lr) * XPAD + ks * 32 + lq * 8];
            #pragma unroll
            for (int m = 0; m < 4; ++m)
                acc[m][nt] = __builtin_amdgcn_mfma_f32_16x16x32_bf16(a[m], bf, acc[m][nt], 0, 0, 0);
        }
    }
    __syncthreads();

    #pragma unroll
    for (int m = 0; m < 4; ++m) {
        int rb = wr + m * 16 + lq * 4;
        float s0 = sBN[0][rb], s1 = sBN[0][rb + 1], s2 = sBN[0][rb + 2], s3 = sBN[0][rb + 3];
        float h0 = sBN[1][rb], h1 = sBN[1][rb + 1], h2 = sBN[1][rb + 2], h3 = sBN[1][rb + 3];
        #pragma unroll
        for (int nt = 0; nt < 4; ++nt) {
            int col = wc + nt * 16 + lr;
            short4v hv;
            hv[0] = f2bf(fmaxf(fmaf(acc[m][nt][0], s0, h0), 0.f));
            hv[1] = f2bf(fmaxf(fmaf(acc[m][nt][1], s1, h1), 0.f));
            hv[2] = f2bf(fmaxf(fmaf(acc[m][nt][2], s2, h2), 0.f));
            hv[3] = f2bf(fmaxf(fmaf(acc[m][nt][3], s3, h3), 0.f));
            *(short4v*)&smem[col * HPAD + rb] = hv;
        }
    }
    __syncthreads();

    f32x4 acc2[4][4];
    #pragma unroll
    for (int m = 0; m < 4; ++m)
        #pragma unroll
        for (int nt = 0; nt < 4; ++nt) acc2[m][nt] = (f32x4){0.f, 0.f, 0.f, 0.f};
    #pragma unroll
    for (int ks = 0; ks < 4; ++ks) {
        bf16x8 a[4];
        #pragma unroll
        for (int m = 0; m < 4; ++m)
            a[m] = *(const bf16x8*)&W2p[(wr + m * 16 + lr) * C1_ + ks * 32 + lq * 8];
        #pragma unroll
        for (int nt = 0; nt < 4; ++nt) {
            bf16x8 bf = *(const bf16x8*)&smem[(wc + nt * 16 + lr) * HPAD + ks * 32 + lq * 8];
            #pragma unroll
            for (int m = 0; m < 4; ++m)
                acc2[m][nt] = __builtin_amdgcn_mfma_f32_16x16x32_bf16(a[m], bf, acc2[m][nt], 0, 0, 0);
        }
    }

    #pragma unroll
    for (int m = 0; m < 4; ++m) {
        int rb = wr + m * 16 + lq * 4;
        float s0 = sBN[2][rb], s1 = sBN[2][rb + 1], s2 = sBN[2][rb + 2], s3 = sBN[2][rb + 3];
        float h0 = sBN[3][rb], h1 = sBN[3][rb + 1], h2 = sBN[3][rb + 2], h3 = sBN[3][rb + 3];
        #pragma unroll
        for (int lp = 0; lp < 2; ++lp) {
            int n = n0 + (w >> 1) * 2 + lp;
            float v0 = fmaxf(fmaf(acc2[m][2 * lp][0], s0, h0), fmaf(acc2[m][2 * lp + 1][0], s0, h0));
            float v1 = fmaxf(fmaf(acc2[m][2 * lp][1], s1, h1), fmaf(acc2[m][2 * lp + 1][1], s1, h1));
            float v2 = fmaxf(fmaf(acc2[m][2 * lp][2], s2, h2), fmaf(acc2[m][2 * lp + 1][2], s2, h2));
            float v3 = fmaxf(fmaf(acc2[m][2 * lp][3], s3, h3), fmaf(acc2[m][2 * lp + 1][3], s3, h3));
            #pragma unroll
            for (int st = 1; st <= 8; st <<= 1) {
                v0 = fmaxf(v0, __shfl_xor(v0, st, 64));
                v1 = fmaxf(v1, __shfl_xor(v1, st, 64));
                v2 = fmaxf(v2, __shfl_xor(v2, st, 64));
                v3 = fmaxf(v3, __shfl_xor(v3, st, 64));
            }
            if (lr == 0) {
                out[((size_t)(b * C2_ + rb))     * N_ + n] = fmaxf(v0, 0.f);
                out[((size_t)(b * C2_ + rb + 1)) * N_ + n] = fmaxf(v1, 0.f);
                out[((size_t)(b * C2_ + rb + 2)) * N_ + n] = fmaxf(v2, 0.f);
                out[((size_t)(b * C2_ + rb + 3)) * N_ + n] = fmaxf(v3, 0.f);
            }
        }
    }
}

extern "C" void kernel_launch(void* const* d_in, const int* in_sizes, int n_in,
                              void* d_out, int out_size, void* d_ws, size_t ws_size,
                              hipStream_t stream) {
    const float* p   = (const float*)d_in[0];
    const float* f   = (const float*)d_in[1];
    const float* W1  = (const float*)d_in[2];
    const float* g1  = (const float*)d_in[3];
    const float* bb1 = (const float*)d_in[4];
    const float* m1  = (const float*)d_in[5];
    const float* v1  = (const float*)d_in[6];
    const float* W2  = (const float*)d_in[7];
    const float* g2  = (const float*)d_in[8];
    const float* bb2 = (const float*)d_in[9];
    const float* m2  = (const float*)d_in[10];
    const float* v2  = (const float*)d_in[11];
    float* out = (float*)d_out;

    char* ws = (char*)d_ws;
    int*   idxbuf = (int*)ws;                           // 2 MB
    short* fT  = (short*)(ws + (2 << 20));              // 2 MB
    short* W1p = (short*)(ws + (4 << 20));              // 24 KB
    short* W2p = (short*)(ws + (4 << 20) + 0x6000);     // 32 KB
    float* bnv = (float*)(ws + (4 << 20) + 0xE000);     // 2 KB
    char*  gm  = ws + (4 << 20) + 0x10000;              // grid metadata
    int* counts  = (int*)gm;                            // 2*256 ints
    int* cursors = (int*)(gm + 0x800);                  // 2*256 ints
    int* starts  = (int*)(gm + 0x1000);                 // 2*256 ints
    int* lists   = (int*)(gm + 0x2000);                 // 2*8192 ints

    hipMemsetAsync(gm, 0, 0x1000, stream);              // counts + cursors
    prep_kernel<<<CBLK0 + 64, 256, 0, stream>>>(
        p, f, fT, counts, W1, g1, bb1, m1, v1, W2, g2, bb2, m2, v2,
        W1p, W2p, bnv);
    prefix_kernel<<<1, 128, 0, stream>>>(counts, starts);
    scatter_kernel<<<64, 256, 0, stream>>>(p, starts, cursors, lists);
    grid_query_kernel<<<(B_ * N_) / 4, 256, 0, stream>>>(p, starts, lists, idxbuf);
    fused_mfma_kernel<<<(B_ * N_) / 4, 256, 0, stream>>>(
        p, idxbuf, fT, W1p, W2p, bnv, out);
}